// Round 5
// baseline (410.195 us; speedup 1.0000x reference)
//
#include <hip/hip_runtime.h>

#define NB    4096
#define TSTEP 256
#define DTC   0.01f

typedef float v2f __attribute__((ext_vector_type(2)));
typedef float v4f __attribute__((ext_vector_type(4)));

// tanh(a) = (E-1)/(E+1), E = exp(2a) via v_exp_f32 + v_rcp_f32 (upper clamp only)
__device__ __forceinline__ float fast_tanh(float a) {
    float t = fminf(a * 2.885390082f, 126.0f);   // 2*log2(e)*a
    float E = __builtin_amdgcn_exp2f(t);
    return (E - 1.0f) * __builtin_amdgcn_rcpf(E + 1.0f);
}
// exp(a), |a| small here
__device__ __forceinline__ float fast_exp(float a) {
    return __builtin_amdgcn_exp2f(a * 1.44269504f);
}
// guaranteed packed fp32 FMA: acc = a*b + acc (2 lanes of fp32 per instr)
__device__ __forceinline__ void pk_fma(v2f& acc, v2f a, v2f b) {
    asm("v_pk_fma_f32 %0, %1, %2, %0" : "+v"(acc) : "v"(a), "v"(b));
}

__global__ void __launch_bounds__(64) __attribute__((amdgpu_waves_per_eu(4, 4)))
koopman_kernel(const float* __restrict__ x,
               const float* __restrict__ Wc1, const float* __restrict__ bc1,
               const float* __restrict__ Wc2, const float* __restrict__ bc2,
               const float* __restrict__ Wr1, const float* __restrict__ br1,
               const float* __restrict__ Wr2, const float* __restrict__ br2,
               float* __restrict__ out)
{
    const int lane = threadIdx.x;            // 0..63 = output feature
    const int blk  = blockIdx.x;             // 0..NB-1, one element per wave

    __shared__ __align__(16) float lds_y[64];
    __shared__ __align__(16) float lds_u[64];

    const bool is_c = (lane < 48);

    // ---- persistent weights as float2 pairs (SROA-friendly scalar builds) ----
    v2f w1[32], w2[24];
    float b1, b2;
    {
        const float* p1 = is_c ? (Wc1 + lane * 64) : (Wr1 + (lane - 48) * 64);
        #pragma unroll
        for (int k = 0; k < 32; ++k) {
            v2f tv; tv.x = p1[2*k]; tv.y = p1[2*k + 1]; w1[k] = tv;
        }
        const float* p2 = is_c ? (Wc2 + lane * 48) : (Wr2 + (lane - 48) * 16);
        #pragma unroll
        for (int k = 0; k < 24; ++k) {
            const bool valid = is_c || (k >= 16);          // r-lanes: only last 8 pairs real
            const int  kk    = is_c ? 2*k : (k >= 16 ? 2*k - 32 : 0);
            v2f tv; tv.x = valid ? p2[kk] : 0.0f; tv.y = valid ? p2[kk + 1] : 0.0f;
            w2[k] = tv;
        }
        b1 = is_c ? bc1[lane] : br1[lane - 48];
        b2 = is_c ? bc2[lane] : br2[lane - 48];
    }
    // layer-2 input window: c-lanes read u[0..47]; r-lanes read u[16..63] with
    // w2[0..15]=0 so only u[48..63] (their own tanh block) contributes.
    const int   ubase = is_c ? 0 : 16;
    const float sgn   = (lane & 1) ? 1.0f : -1.0f;
    const bool  odd   = (lane & 1) != 0;

    // ---- init state ----
    float ysel = x[blk * 64 + lane];
    lds_y[lane] = ysel;
    float* pout = out + (size_t)blk * (TSTEP * 64) + lane;

    // Single-wave workgroup, wave-synchronous LDS: the per-wave in-order DS pipe
    // plus compiler alias-ordering on lds_y/lds_u makes barriers unnecessary.
    for (int t = 0; t < TSTEP; ++t) {
        // ---- layer 1: u = tanh(W1 @ y + b1), uniform-address b128 broadcasts ----
        v2f accA = {b1, 0.0f}, accB = {0.0f, 0.0f};
        #pragma unroll
        for (int k = 0; k < 16; ++k) {
            const v4f q = *reinterpret_cast<const v4f*>(&lds_y[k * 4]);
            const v2f lo = __builtin_shufflevector(q, q, 0, 1);
            const v2f hi = __builtin_shufflevector(q, q, 2, 3);
            pk_fma(accA, w1[2*k],     lo);
            pk_fma(accB, w1[2*k + 1], hi);
        }
        {
            const v2f s2 = accA + accB;
            lds_u[lane] = fast_tanh(s2.x + s2.y);
        }

        // ---- layer 2: co/re = W2 @ u + b2 ----
        v2f acc2A = {b2, 0.0f}, acc2B = {0.0f, 0.0f};
        #pragma unroll
        for (int k = 0; k < 12; ++k) {
            const v4f q = *reinterpret_cast<const v4f*>(&lds_u[ubase + k * 4]);
            const v2f lo = __builtin_shufflevector(q, q, 0, 1);
            const v2f hi = __builtin_shufflevector(q, q, 2, 3);
            pk_fma(acc2A, w2[2*k],     lo);
            pk_fma(acc2B, w2[2*k + 1], hi);
        }
        const v2f c2 = acc2A + acc2B;
        const float co = c2.x + c2.y;

        // ---- pointwise update ----
        const float other = __shfl_xor(co, 1, 64);
        const float mu = odd ? other : co;     // even slot of pair
        const float om = odd ? co    : other;  // odd slot of pair
        const float scale = fast_exp(DTC * mu);
        const float omr = om * 1.59154943e-3f; // dt*om / (2*pi): v_sin takes revolutions
        const float sv = __builtin_amdgcn_sinf(omr) * scale;
        const float cv = __builtin_amdgcn_cosf(omr) * scale;
        const float yo = __shfl_xor(ysel, 1, 64);
        // even lane: c*y_self - s*y_partner ; odd lane: c*y_self + s*y_partner
        const float ycnew = fmaf(cv, ysel, sgn * sv * yo);
        const float yrnew = fast_exp(DTC * co) * ysel;
        const float ynew  = is_c ? ycnew : yrnew;
        ysel = ynew;
        lds_y[lane] = ynew;
        *pout = ynew;
        pout += 64;
    }
}

extern "C" void kernel_launch(void* const* d_in, const int* in_sizes, int n_in,
                              void* d_out, int out_size, void* d_ws, size_t ws_size,
                              hipStream_t stream) {
    const float* x   = (const float*)d_in[0];
    const float* Wc1 = (const float*)d_in[1];
    const float* bc1 = (const float*)d_in[2];
    const float* Wc2 = (const float*)d_in[3];
    const float* bc2 = (const float*)d_in[4];
    const float* Wr1 = (const float*)d_in[5];
    const float* br1 = (const float*)d_in[6];
    const float* Wr2 = (const float*)d_in[7];
    const float* br2 = (const float*)d_in[8];
    float* out = (float*)d_out;

    koopman_kernel<<<dim3(NB), dim3(64), 0, stream>>>(
        x, Wc1, bc1, Wc2, bc2, Wr1, br1, Wr2, br2, out);
}